// Round 6
// baseline (231.150 us; speedup 1.0000x reference)
//
#include <hip/hip_runtime.h>
#include <hip/hip_bf16.h>

#define D_MODEL 768
#define N_HEADS 12
#define D_HEADK 64
#define BB 2
#define TT 2048
#define M_TOK (BB*TT)          // 4096
#define N_QKV (3*D_MODEL)      // 2304

using f32x4  = __attribute__((ext_vector_type(4))) float;
using f32x16 = __attribute__((ext_vector_type(16))) float;
using s16x8  = __attribute__((ext_vector_type(8))) short;

__device__ __forceinline__ float fast_exp2(float x) {
    return __builtin_amdgcn_exp2f(x);
}

__device__ __forceinline__ unsigned short f2bf(float f) {
    union { float f; unsigned u; } v; v.f = f;
    unsigned r = v.u + 0x7FFFu + ((v.u >> 16) & 1u);
    return (unsigned short)(r >> 16);
}

__device__ __forceinline__ unsigned cvtpk_bf16(float lo, float hi) {
    unsigned d;
    asm("v_cvt_pk_bf16_f32 %0, %1, %2" : "=v"(d) : "v"(lo), "v"(hi));
    return d;
}

// ---------------- X fp32 -> bf16 prepass ------------------------------------
__global__ void xbf_kernel(const float* __restrict__ X, unsigned short* __restrict__ Xb) {
    int idx = (blockIdx.x * 256 + threadIdx.x) * 8;
    float4 v0 = *(const float4*)&X[idx];
    float4 v1 = *(const float4*)&X[idx + 4];
    ushort4 u0, u1;
    u0.x = f2bf(v0.x); u0.y = f2bf(v0.y); u0.z = f2bf(v0.z); u0.w = f2bf(v0.w);
    u1.x = f2bf(v1.x); u1.y = f2bf(v1.y); u1.z = f2bf(v1.z); u1.w = f2bf(v1.w);
    *(ushort4*)&Xb[idx]     = u0;
    *(ushort4*)&Xb[idx + 4] = u1;
}

// ---------------- weight transpose: W [K][N] fp32 -> Wt [N][K] bf16 ----------
__global__ void wtrans_kernel(const float* __restrict__ Wa, const float* __restrict__ Wp,
                              unsigned short* __restrict__ Wta, unsigned short* __restrict__ Wtp) {
    const float* W; unsigned short* Wt; int N;
    if (blockIdx.z == 0) { W = Wa; Wt = Wta; N = N_QKV; }
    else                 { W = Wp; Wt = Wtp; N = D_MODEL; }
    int bx = blockIdx.x * 32;  // n
    if (bx >= N) return;
    int by = blockIdx.y * 32;  // k
    __shared__ float tile[32][33];
    int tx = threadIdx.x & 31;
    int ty = threadIdx.x >> 5;   // 0..7
    #pragma unroll
    for (int i = ty; i < 32; i += 8)
        tile[i][tx] = W[(size_t)(by + i) * N + bx + tx];
    __syncthreads();
    #pragma unroll
    for (int i = ty; i < 32; i += 8)
        Wt[(size_t)(bx + i) * D_MODEL + by + tx] = f2bf(tile[tx][i]);
}

// ---------------- QKV GEMM: Xb[4096,768] x Wt[2304,768] -> Q,K,V (row-major)-
__launch_bounds__(256)
__global__ void qkv_kernel(const unsigned short* __restrict__ Xb, const unsigned short* __restrict__ Wt,
                           const float* __restrict__ bias,
                           unsigned short* __restrict__ Qw, unsigned short* __restrict__ Kw,
                           unsigned short* __restrict__ Vw) {
    __shared__ unsigned short As[128][40];
    __shared__ unsigned short Bs[128][40];
    const int m0 = blockIdx.y * 128;
    const int n0 = blockIdx.x * 128;
    const int tid = threadIdx.x;
    const int l  = tid & 63;
    const int w  = tid >> 6;
    const int wr = w >> 1, wc = w & 1;
    const int lr = l & 15, lk = (l >> 4) * 8, li = (l >> 4) * 4;

    f32x4 acc[4][4] = {};
    for (int kt = 0; kt < D_MODEL; kt += 32) {
        #pragma unroll
        for (int p = 0; p < 2; ++p) {
            int ch = tid * 2 + p;
            int r = ch >> 2;
            int c = (ch & 3) * 8;
            *(int4*)&As[r][c] = *(const int4*)&Xb[(size_t)(m0 + r) * D_MODEL + kt + c];
            *(int4*)&Bs[r][c] = *(const int4*)&Wt[(size_t)(n0 + r) * D_MODEL + kt + c];
        }
        __syncthreads();
        s16x8 a[4], bf[4];
        #pragma unroll
        for (int mi = 0; mi < 4; ++mi)
            a[mi] = *(const s16x8*)&As[wr*64 + mi*16 + lr][lk];
        #pragma unroll
        for (int ni = 0; ni < 4; ++ni)
            bf[ni] = *(const s16x8*)&Bs[wc*64 + ni*16 + lr][lk];
        #pragma unroll
        for (int mi = 0; mi < 4; ++mi)
            #pragma unroll
            for (int ni = 0; ni < 4; ++ni)
                acc[mi][ni] = __builtin_amdgcn_mfma_f32_16x16x32_bf16(a[mi], bf[ni], acc[mi][ni], 0, 0, 0);
        __syncthreads();
    }
    // epilogue: scatter to Q (pre-scaled by 1/8 * log2e), K, V  (all row-major)
    #pragma unroll
    for (int ni = 0; ni < 4; ++ni) {
        int ng = n0 + wc*64 + ni*16 + lr;
        int mat = ng / D_MODEL;       // uniform per block (128 | 768)
        int hd  = ng % D_MODEL;
        int h = hd >> 6, d = hd & 63;
        float bv = bias[ng];
        #pragma unroll
        for (int mi = 0; mi < 4; ++mi) {
            #pragma unroll
            for (int i = 0; i < 4; ++i) {
                int t  = m0 + wr*64 + mi*16 + li + i;
                int b  = t >> 11, tq = t & 2047;
                float val = acc[mi][ni][i] + bv;
                size_t off = ((size_t)(b*N_HEADS + h)*TT + tq)*64 + d;
                if (mat == 0)      Qw[off] = f2bf(val * 0.18033688f);
                else if (mat == 1) Kw[off] = f2bf(val);
                else               Vw[off] = f2bf(val);
            }
        }
    }
}

// ---------------- V transpose: Vw[bh][t][64] -> Vt[bh][64][t] ---------------
__launch_bounds__(256)
__global__ void vtrans_kernel(const unsigned short* __restrict__ Vw, unsigned short* __restrict__ Vt) {
    __shared__ unsigned short tile[64][65];
    const int bh = blockIdx.y;
    const int t0 = blockIdx.x * 64;
    const int tid = threadIdx.x;
    const int srow = tid >> 3;          // 0..31
    const int scol = (tid & 7) * 8;     // 0..56
    const unsigned short* src = Vw + (size_t)bh * TT * 64;
    unsigned short* dst = Vt + (size_t)bh * 64 * TT;
    *(int4*)&tile[srow][scol]    = *(const int4*)&src[(size_t)(t0 + srow) * 64 + scol];
    *(int4*)&tile[srow+32][scol] = *(const int4*)&src[(size_t)(t0 + srow + 32) * 64 + scol];
    __syncthreads();
    s16x8 a0, a1;
    #pragma unroll
    for (int j = 0; j < 8; ++j) {
        a0[j] = (short)tile[scol + j][srow];
        a1[j] = (short)tile[scol + j][srow + 32];
    }
    *(s16x8*)&dst[(size_t)srow * TT + t0 + scol]        = a0;
    *(s16x8*)&dst[(size_t)(srow + 32) * TT + t0 + scol] = a1;
}

// ---------------- causal flash attention: 1 wave / 32 q-rows, no LDS --------
// Swapped QK^T (S^T = K x Q^T): lane owns q-row (lane&31); softmax lane-local.
// K/V read directly from global (L1/L2-resident, 512KB per bh); K prefetched
// one subtile ahead; V issued at iter top to land under QK+softmax.
// P -> bf16 A-frag in-register via v_cvt_pk_bf16_f32 + v_permlane32_swap_b32.
// Scores in log2-units (Q pre-scaled by 0.125*log2e); exp via v_exp_f32.
__launch_bounds__(64)
__global__ void attn_kernel(const unsigned short* __restrict__ Q,
                            const unsigned short* __restrict__ Kk,
                            const unsigned short* __restrict__ Vt,
                            unsigned short* __restrict__ Y) {
    const int bh = blockIdx.y;          // 0..23
    const int qci = gridDim.x - 1 - blockIdx.x;   // longest blocks first
    const int q0 = qci * 32;
    const int b = bh / N_HEADS, h = bh % N_HEADS;
    const int l = threadIdx.x;
    const int lq = l & 31;              // q-row / d-col / k-row lane index
    const int hi = l >> 5;

    const unsigned short* Qp = Q  + (size_t)bh * TT * 64;
    const unsigned short* Kp = Kk + (size_t)bh * TT * 64;
    const unsigned short* Vp = Vt + (size_t)bh * 64 * TT;

    // Q fragments: lane holds its q-row's d-slice; pre-select by hi so all
    // later indexing is compile-time.
    s16x8 qsel[4];
    {
        const unsigned short* qrow = &Qp[(size_t)(q0 + lq) * 64];
        #pragma unroll
        for (int t = 0; t < 4; ++t) {
            s16x8 qlo = *(const s16x8*)&qrow[16*t];
            s16x8 qhi = *(const s16x8*)&qrow[16*t + 8];
            qsel[t] = hi ? qhi : qlo;
        }
    }

    float mi = -1e30f, si = 0.f;
    f32x16 o0 = {}, o1 = {};

    // preload K A-frags for kk=0
    s16x8 ka0 = *(const s16x8*)&Kp[(size_t)lq * 64 + 8*hi];
    s16x8 ka1 = *(const s16x8*)&Kp[(size_t)lq * 64 + 16 + 8*hi];
    s16x8 ka2 = *(const s16x8*)&Kp[(size_t)lq * 64 + 32 + 8*hi];
    s16x8 ka3 = *(const s16x8*)&Kp[(size_t)lq * 64 + 48 + 8*hi];

    for (int kk = 0; kk <= q0; kk += 32) {
        // V B-frags for this subtile (issue early; consumed after softmax)
        const int kc = kk + 8*hi;
        s16x8 vb00 = *(const s16x8*)&Vp[(size_t)lq * TT + kc];
        s16x8 vb01 = *(const s16x8*)&Vp[(size_t)(32 + lq) * TT + kc];
        s16x8 vb10 = *(const s16x8*)&Vp[(size_t)lq * TT + kc + 16];
        s16x8 vb11 = *(const s16x8*)&Vp[(size_t)(32 + lq) * TT + kc + 16];

        // ---- QK^T (swapped): S^T[k][q]; lane: q=lq, k=(r&3)+8(r>>2)+4hi ----
        f32x16 s = {};
        s = __builtin_amdgcn_mfma_f32_32x32x16_bf16(ka0, qsel[0], s, 0, 0, 0);
        s = __builtin_amdgcn_mfma_f32_32x32x16_bf16(ka1, qsel[1], s, 0, 0, 0);
        s = __builtin_amdgcn_mfma_f32_32x32x16_bf16(ka2, qsel[2], s, 0, 0, 0);
        s = __builtin_amdgcn_mfma_f32_32x32x16_bf16(ka3, qsel[3], s, 0, 0, 0);

        // prefetch next subtile's K frags (lands under softmax+PV)
        if (kk + 32 <= q0) {
            const unsigned short* krow = &Kp[(size_t)(kk + 32 + lq) * 64 + 8*hi];
            ka0 = *(const s16x8*)&krow[0];
            ka1 = *(const s16x8*)&krow[16];
            ka2 = *(const s16x8*)&krow[32];
            ka3 = *(const s16x8*)&krow[48];
        }

        if (kk == q0) {   // diagonal subtile: causal mask
            #pragma unroll
            for (int r = 0; r < 16; ++r) {
                const int kloc = (r & 3) + 8*(r >> 2) + 4*hi;
                if (kloc > lq) s[r] = -1e30f;
            }
        }

        // ---- online softmax, lane-local (tree reductions) ----
        float m0a = fmaxf(s[0], s[1]),  m1a = fmaxf(s[2], s[3]);
        float m2a = fmaxf(s[4], s[5]),  m3a = fmaxf(s[6], s[7]);
        float m4a = fmaxf(s[8], s[9]),  m5a = fmaxf(s[10], s[11]);
        float m6a = fmaxf(s[12], s[13]), m7a = fmaxf(s[14], s[15]);
        float lm = fmaxf(fmaxf(fmaxf(m0a, m1a), fmaxf(m2a, m3a)),
                         fmaxf(fmaxf(m4a, m5a), fmaxf(m6a, m7a)));
        if (!__all(lm <= mi + 11.5f)) {    // rare rescale path
            float pm = fmaxf(lm, __shfl_xor(lm, 32));
            float mn = fmaxf(mi, pm);
            float sf = fast_exp2(mi - mn);
            si *= sf;
            #pragma unroll
            for (int r = 0; r < 16; ++r) {
                const int qloc = (r & 3) + 8*(r >> 2) + 4*hi;
                float sfq = __shfl(sf, qloc);
                o0[r] *= sfq; o1[r] *= sfq;
            }
            mi = mn;
        }
        float e[16];
        #pragma unroll
        for (int r = 0; r < 16; ++r) e[r] = fast_exp2(s[r] - mi);
        float p0 = (e[0] + e[1]) + (e[2] + e[3]);
        float p1 = (e[4] + e[5]) + (e[6] + e[7]);
        float p2 = (e[8] + e[9]) + (e[10] + e[11]);
        float p3 = (e[12] + e[13]) + (e[14] + e[15]);
        si += (p0 + p1) + (p2 + p3);

        // ---- P A-frags in-register + PV ----
        {
            unsigned c0 = cvtpk_bf16(e[0], e[1]);
            unsigned c1 = cvtpk_bf16(e[2], e[3]);
            unsigned c2 = cvtpk_bf16(e[4], e[5]);
            unsigned c3 = cvtpk_bf16(e[6], e[7]);
            asm("v_permlane32_swap_b32 %0, %1" : "+v"(c0), "+v"(c2));
            asm("v_permlane32_swap_b32 %0, %1" : "+v"(c1), "+v"(c3));
            union { unsigned u[4]; s16x8 v; } pa;
            pa.u[0] = c0; pa.u[1] = c1; pa.u[2] = c2; pa.u[3] = c3;
            o0 = __builtin_amdgcn_mfma_f32_32x32x16_bf16(pa.v, vb00, o0, 0, 0, 0);
            o1 = __builtin_amdgcn_mfma_f32_32x32x16_bf16(pa.v, vb01, o1, 0, 0, 0);
        }
        {
            unsigned c0 = cvtpk_bf16(e[8], e[9]);
            unsigned c1 = cvtpk_bf16(e[10], e[11]);
            unsigned c2 = cvtpk_bf16(e[12], e[13]);
            unsigned c3 = cvtpk_bf16(e[14], e[15]);
            asm("v_permlane32_swap_b32 %0, %1" : "+v"(c0), "+v"(c2));
            asm("v_permlane32_swap_b32 %0, %1" : "+v"(c1), "+v"(c3));
            union { unsigned u[4]; s16x8 v; } pa;
            pa.u[0] = c0; pa.u[1] = c1; pa.u[2] = c2; pa.u[3] = c3;
            o0 = __builtin_amdgcn_mfma_f32_32x32x16_bf16(pa.v, vb10, o0, 0, 0, 0);
            o1 = __builtin_amdgcn_mfma_f32_32x32x16_bf16(pa.v, vb11, o1, 0, 0, 0);
        }
    }
    // ---- epilogue: normalize + store ----
    float sfull = si + __shfl_xor(si, 32);
    float invf = 1.f / sfull;
    #pragma unroll
    for (int r = 0; r < 16; ++r) {
        const int qloc = (r & 3) + 8*(r >> 2) + 4*hi;
        float iv = __shfl(invf, qloc);
        size_t row = (size_t)(b*TT + q0 + qloc) * D_MODEL + h*64;
        Y[row + lq]      = f2bf(o0[r] * iv);
        Y[row + 32 + lq] = f2bf(o1[r] * iv);
    }
}

// ---------------- proj GEMM: Y[4096,768]bf16 x Wt[768,768]bf16 + b -> fp32 --
__launch_bounds__(256)
__global__ void proj_kernel(const unsigned short* __restrict__ Y, const unsigned short* __restrict__ Wt,
                            const float* __restrict__ bias, float* __restrict__ Out) {
    __shared__ unsigned short As[128][40];
    __shared__ unsigned short Bs[128][40];
    const int m0 = blockIdx.y * 128;
    const int n0 = blockIdx.x * 128;
    const int tid = threadIdx.x;
    const int l  = tid & 63;
    const int w  = tid >> 6;
    const int wr = w >> 1, wc = w & 1;
    const int lr = l & 15, lk = (l >> 4) * 8, li = (l >> 4) * 4;

    f32x4 acc[4][4] = {};
    for (int kt = 0; kt < D_MODEL; kt += 32) {
        #pragma unroll
        for (int p = 0; p < 2; ++p) {
            int ch = tid * 2 + p;
            int r = ch >> 2;
            int c = (ch & 3) * 8;
            *(int4*)&As[r][c] = *(const int4*)&Y[(size_t)(m0 + r) * D_MODEL + kt + c];
            *(int4*)&Bs[r][c] = *(const int4*)&Wt[(size_t)(n0 + r) * D_MODEL + kt + c];
        }
        __syncthreads();
        s16x8 a[4], bf[4];
        #pragma unroll
        for (int mi = 0; mi < 4; ++mi)
            a[mi] = *(const s16x8*)&As[wr*64 + mi*16 + lr][lk];
        #pragma unroll
        for (int ni = 0; ni < 4; ++ni)
            bf[ni] = *(const s16x8*)&Bs[wc*64 + ni*16 + lr][lk];
        #pragma unroll
        for (int mi = 0; mi < 4; ++mi)
            #pragma unroll
            for (int ni = 0; ni < 4; ++ni)
                acc[mi][ni] = __builtin_amdgcn_mfma_f32_16x16x32_bf16(a[mi], bf[ni], acc[mi][ni], 0, 0, 0);
        __syncthreads();
    }
    #pragma unroll
    for (int ni = 0; ni < 4; ++ni) {
        int ng = n0 + wc*64 + ni*16 + lr;
        float bv = bias[ng];
        #pragma unroll
        for (int mj = 0; mj < 4; ++mj)
            #pragma unroll
            for (int i = 0; i < 4; ++i) {
                int t = m0 + wr*64 + mj*16 + li + i;
                Out[(size_t)t*D_MODEL + ng] = acc[mj][ni][i] + bv;
            }
    }
}

extern "C" void kernel_launch(void* const* d_in, const int* in_sizes, int n_in,
                              void* d_out, int out_size, void* d_ws, size_t ws_size,
                              hipStream_t stream) {
    const float* x      = (const float*)d_in[0];
    const float* w_attn = (const float*)d_in[1];
    const float* b_attn = (const float*)d_in[2];
    const float* w_proj = (const float*)d_in[3];
    const float* b_proj = (const float*)d_in[4];
    float* out = (float*)d_out;

    unsigned short* wt_attn = (unsigned short*)d_ws;                       // 2304*768
    unsigned short* wt_proj = wt_attn + (size_t)N_QKV * D_MODEL;           // 768*768
    unsigned short* Qw      = wt_proj + (size_t)D_MODEL * D_MODEL;
    unsigned short* Kw      = Qw + (size_t)M_TOK * D_MODEL;
    unsigned short* Vw      = Kw + (size_t)M_TOK * D_MODEL;
    unsigned short* Yw      = Vw + (size_t)M_TOK * D_MODEL;
    unsigned short* Xb      = Yw + (size_t)M_TOK * D_MODEL;
    unsigned short* Vtw     = Xb;   // Xb dead after qkv_kernel; reuse for V^T

    hipLaunchKernelGGL(xbf_kernel, dim3(M_TOK*D_MODEL/2048), dim3(256), 0, stream, x, Xb);
    hipLaunchKernelGGL(wtrans_kernel, dim3(N_QKV/32, D_MODEL/32, 2), dim3(256), 0, stream,
                       w_attn, w_proj, wt_attn, wt_proj);
    hipLaunchKernelGGL(qkv_kernel, dim3(N_QKV/128, M_TOK/128), dim3(256), 0, stream,
                       Xb, wt_attn, b_attn, Qw, Kw, Vw);
    hipLaunchKernelGGL(vtrans_kernel, dim3(TT/64, BB*N_HEADS), dim3(256), 0, stream,
                       Vw, Vtw);
    hipLaunchKernelGGL(attn_kernel, dim3(TT/32, BB*N_HEADS), dim3(64), 0, stream,
                       Qw, Kw, Vtw, Yw);
    hipLaunchKernelGGL(proj_kernel, dim3(D_MODEL/128, M_TOK/128), dim3(256), 0, stream,
                       Yw, wt_proj, b_proj, out);
}

// Round 7
// 195.230 us; speedup vs baseline: 1.1840x; 1.1840x over previous
//
#include <hip/hip_runtime.h>
#include <hip/hip_bf16.h>

#define D_MODEL 768
#define N_HEADS 12
#define D_HEADK 64
#define BB 2
#define TT 2048
#define M_TOK (BB*TT)          // 4096
#define N_QKV (3*D_MODEL)      // 2304
#define MS_SEG (BB*N_HEADS*TT) // 49152 rows per seg

using f32x4  = __attribute__((ext_vector_type(4))) float;
using f32x16 = __attribute__((ext_vector_type(16))) float;
using s16x8  = __attribute__((ext_vector_type(8))) short;

__device__ __forceinline__ float fast_exp2(float x) {
    return __builtin_amdgcn_exp2f(x);
}

__device__ __forceinline__ unsigned short f2bf(float f) {
    union { float f; unsigned u; } v; v.f = f;
    unsigned r = v.u + 0x7FFFu + ((v.u >> 16) & 1u);
    return (unsigned short)(r >> 16);
}

__device__ __forceinline__ float bf2f(unsigned short u) {
    union { unsigned u; float f; } v; v.u = ((unsigned)u) << 16; return v.f;
}

__device__ __forceinline__ unsigned cvtpk_bf16(float lo, float hi) {
    unsigned d;
    asm("v_cvt_pk_bf16_f32 %0, %1, %2" : "=v"(d) : "v"(lo), "v"(hi));
    return d;
}

// ---------------- X fp32 -> bf16 prepass ------------------------------------
__global__ void xbf_kernel(const float* __restrict__ X, unsigned short* __restrict__ Xb) {
    int idx = (blockIdx.x * 256 + threadIdx.x) * 8;
    float4 v0 = *(const float4*)&X[idx];
    float4 v1 = *(const float4*)&X[idx + 4];
    ushort4 u0, u1;
    u0.x = f2bf(v0.x); u0.y = f2bf(v0.y); u0.z = f2bf(v0.z); u0.w = f2bf(v0.w);
    u1.x = f2bf(v1.x); u1.y = f2bf(v1.y); u1.z = f2bf(v1.z); u1.w = f2bf(v1.w);
    *(ushort4*)&Xb[idx]     = u0;
    *(ushort4*)&Xb[idx + 4] = u1;
}

// ---------------- weight transpose: W [K][N] fp32 -> Wt [N][K] bf16 ----------
__global__ void wtrans_kernel(const float* __restrict__ Wa, const float* __restrict__ Wp,
                              unsigned short* __restrict__ Wta, unsigned short* __restrict__ Wtp) {
    const float* W; unsigned short* Wt; int N;
    if (blockIdx.z == 0) { W = Wa; Wt = Wta; N = N_QKV; }
    else                 { W = Wp; Wt = Wtp; N = D_MODEL; }
    int bx = blockIdx.x * 32;  // n
    if (bx >= N) return;
    int by = blockIdx.y * 32;  // k
    __shared__ float tile[32][33];
    int tx = threadIdx.x & 31;
    int ty = threadIdx.x >> 5;   // 0..7
    #pragma unroll
    for (int i = ty; i < 32; i += 8)
        tile[i][tx] = W[(size_t)(by + i) * N + bx + tx];
    __syncthreads();
    #pragma unroll
    for (int i = ty; i < 32; i += 8)
        Wt[(size_t)(bx + i) * D_MODEL + by + tx] = f2bf(tile[tx][i]);
}

// ---------------- QKV GEMM: Xb[4096,768] x Wt[2304,768] -> Q,K,V (row-major)-
__launch_bounds__(256)
__global__ void qkv_kernel(const unsigned short* __restrict__ Xb, const unsigned short* __restrict__ Wt,
                           const float* __restrict__ bias,
                           unsigned short* __restrict__ Qw, unsigned short* __restrict__ Kw,
                           unsigned short* __restrict__ Vw) {
    __shared__ unsigned short As[128][40];
    __shared__ unsigned short Bs[128][40];
    const int m0 = blockIdx.y * 128;
    const int n0 = blockIdx.x * 128;
    const int tid = threadIdx.x;
    const int l  = tid & 63;
    const int w  = tid >> 6;
    const int wr = w >> 1, wc = w & 1;
    const int lr = l & 15, lk = (l >> 4) * 8, li = (l >> 4) * 4;

    f32x4 acc[4][4] = {};
    for (int kt = 0; kt < D_MODEL; kt += 32) {
        #pragma unroll
        for (int p = 0; p < 2; ++p) {
            int ch = tid * 2 + p;
            int r = ch >> 2;
            int c = (ch & 3) * 8;
            *(int4*)&As[r][c] = *(const int4*)&Xb[(size_t)(m0 + r) * D_MODEL + kt + c];
            *(int4*)&Bs[r][c] = *(const int4*)&Wt[(size_t)(n0 + r) * D_MODEL + kt + c];
        }
        __syncthreads();
        s16x8 a[4], bf[4];
        #pragma unroll
        for (int mi = 0; mi < 4; ++mi)
            a[mi] = *(const s16x8*)&As[wr*64 + mi*16 + lr][lk];
        #pragma unroll
        for (int ni = 0; ni < 4; ++ni)
            bf[ni] = *(const s16x8*)&Bs[wc*64 + ni*16 + lr][lk];
        #pragma unroll
        for (int mi = 0; mi < 4; ++mi)
            #pragma unroll
            for (int ni = 0; ni < 4; ++ni)
                acc[mi][ni] = __builtin_amdgcn_mfma_f32_16x16x32_bf16(a[mi], bf[ni], acc[mi][ni], 0, 0, 0);
        __syncthreads();
    }
    // epilogue: scatter to Q (pre-scaled by 1/8 * log2e), K, V  (all row-major)
    #pragma unroll
    for (int ni = 0; ni < 4; ++ni) {
        int ng = n0 + wc*64 + ni*16 + lr;
        int mat = ng / D_MODEL;       // uniform per block (128 | 768)
        int hd  = ng % D_MODEL;
        int h = hd >> 6, d = hd & 63;
        float bv = bias[ng];
        #pragma unroll
        for (int mi = 0; mi < 4; ++mi) {
            #pragma unroll
            for (int i = 0; i < 4; ++i) {
                int t  = m0 + wr*64 + mi*16 + li + i;
                int b  = t >> 11, tq = t & 2047;
                float val = acc[mi][ni][i] + bv;
                size_t off = ((size_t)(b*N_HEADS + h)*TT + tq)*64 + d;
                if (mat == 0)      Qw[off] = f2bf(val * 0.18033688f);
                else if (mat == 1) Kw[off] = f2bf(val);
                else               Vw[off] = f2bf(val);
            }
        }
    }
}

// ---------------- V transpose: Vw[bh][t][64] -> Vt[bh][64][t] ---------------
__launch_bounds__(256)
__global__ void vtrans_kernel(const unsigned short* __restrict__ Vw, unsigned short* __restrict__ Vt) {
    __shared__ unsigned short tile[64][65];
    const int bh = blockIdx.y;
    const int t0 = blockIdx.x * 64;
    const int tid = threadIdx.x;
    const int srow = tid >> 3;          // 0..31
    const int scol = (tid & 7) * 8;     // 0..56
    const unsigned short* src = Vw + (size_t)bh * TT * 64;
    unsigned short* dst = Vt + (size_t)bh * 64 * TT;
    *(int4*)&tile[srow][scol]    = *(const int4*)&src[(size_t)(t0 + srow) * 64 + scol];
    *(int4*)&tile[srow+32][scol] = *(const int4*)&src[(size_t)(t0 + srow + 32) * 64 + scol];
    __syncthreads();
    s16x8 a0, a1;
    #pragma unroll
    for (int j = 0; j < 8; ++j) {
        a0[j] = (short)tile[scol + j][srow];
        a1[j] = (short)tile[scol + j][srow + 32];
    }
    *(s16x8*)&dst[(size_t)srow * TT + t0 + scol]        = a0;
    *(s16x8*)&dst[(size_t)(srow + 32) * TT + t0 + scol] = a1;
}

// ---------------- causal flash attention, SPLIT-K (2 segments) --------------
// r5 proven core: 4 waves x 32 q-rows (128-q chunk), 64-k LDS tiles, swapped
// QK^T 32x32 MFMA, lane-local softmax, in-register P via cvt_pk+permlane.
// Each chunk's 2(qci+1) k-tiles split across 2 blocks; partials (unnormalized
// bf16 O, f32 m/s per q-row) merged by merge_kernel.
__device__ __forceinline__ int swz(int r, int c) { return r*64 + (c ^ ((r & 7) << 3)); }

__launch_bounds__(256)
__global__ void attn_kernel(const unsigned short* __restrict__ Q,
                            const unsigned short* __restrict__ Kk,
                            const unsigned short* __restrict__ Vt,
                            unsigned short* __restrict__ oA,
                            unsigned short* __restrict__ oB,
                            float* __restrict__ ms) {
    __shared__ unsigned short Ks[64*64];
    __shared__ unsigned short Vs[64*64];
    const int bh = blockIdx.y;          // 0..23
    const int px = blockIdx.x;          // 0..31
    const int qci = 15 - (px >> 1);     // longest chunks first
    const int seg = px & 1;
    const int q0 = qci * 128;
    const int b = bh / N_HEADS, h = bh % N_HEADS;
    const int tid = threadIdx.x;
    const int l  = tid & 63;
    const int w  = tid >> 6;            // wave 0..3
    const int lq = l & 31;
    const int hi = l >> 5;
    const int srow = tid >> 3;          // 0..31 (staging)
    const int scol = (tid & 7) * 8;     // 0..56
    const int qw0 = q0 + w * 32;        // this wave's first q-row

    const unsigned short* Qp = Q  + (size_t)bh * TT * 64;
    const unsigned short* Kp = Kk + (size_t)bh * TT * 64;
    const unsigned short* Vp = Vt + (size_t)bh * 64 * TT;

    // k-tile range for this segment
    const int ntiles  = 2 * (qci + 1);
    const int n0      = ntiles >> 1;    // = qci+1
    const int t_begin = seg ? n0 : 0;
    const int t_end   = seg ? ntiles : n0;

    // Q fragments (pre-selected by hi so indexing is compile-time)
    s16x8 qsel[4];
    {
        const unsigned short* qrow = &Qp[(size_t)(qw0 + lq) * 64];
        #pragma unroll
        for (int t = 0; t < 4; ++t) {
            s16x8 qlo = *(const s16x8*)&qrow[16*t];
            s16x8 qhi = *(const s16x8*)&qrow[16*t + 8];
            qsel[t] = hi ? qhi : qlo;
        }
    }

    float mi = -1e30f, si = 0.f;
    f32x16 o0 = {}, o1 = {};

    // prefetch first tile of the segment
    const int kb0 = t_begin * 64;
    int4 kp0 = *(const int4*)&Kp[(size_t)(kb0 + srow) * 64 + scol];
    int4 kp1 = *(const int4*)&Kp[(size_t)(kb0 + srow + 32) * 64 + scol];
    int4 vp0 = *(const int4*)&Vp[(size_t)srow * TT + kb0 + scol];
    int4 vp1 = *(const int4*)&Vp[(size_t)(srow + 32) * TT + kb0 + scol];

    for (int it = t_begin; it < t_end; ++it) {
        const int kt = it * 64;
        __syncthreads();                       // prev compute done, LDS free
        *(int4*)&Ks[swz(srow,      scol)] = kp0;
        *(int4*)&Ks[swz(srow + 32, scol)] = kp1;
        *(int4*)&Vs[swz(srow,      scol)] = vp0;
        *(int4*)&Vs[swz(srow + 32, scol)] = vp1;
        __syncthreads();                       // tile ready
        if (it + 1 < t_end) {                  // prefetch next (hides latency)
            const int k2 = kt + 64;
            kp0 = *(const int4*)&Kp[(size_t)(k2 + srow) * 64 + scol];
            kp1 = *(const int4*)&Kp[(size_t)(k2 + srow + 32) * 64 + scol];
            vp0 = *(const int4*)&Vp[(size_t)srow * TT + k2 + scol];
            vp1 = *(const int4*)&Vp[(size_t)(srow + 32) * TT + k2 + scol];
        }
        #pragma unroll
        for (int kti = 0; kti < 2; ++kti) {
            const int kk = kt + kti * 32;
            if (kk > qw0) continue;            // wave-uniform: post-diagonal
            const bool diag = (kk == qw0);
            // ---- QK^T (swapped): S^T[k][q]; lane: q=lq, k=(r&3)+8(r>>2)+4hi
            f32x16 s = {};
            #pragma unroll
            for (int t = 0; t < 4; ++t) {
                s16x8 a = *(const s16x8*)&Ks[swz(kti*32 + lq, 16*t + 8*hi)];
                s = __builtin_amdgcn_mfma_f32_32x32x16_bf16(a, qsel[t], s, 0, 0, 0);
            }
            if (diag) {
                #pragma unroll
                for (int r = 0; r < 16; ++r) {
                    const int kloc = (r & 3) + 8*(r >> 2) + 4*hi;
                    if (kloc > lq) s[r] = -1e30f;
                }
            }
            // ---- online softmax, lane-local ----
            float lm = s[0];
            #pragma unroll
            for (int r = 1; r < 16; ++r) lm = fmaxf(lm, s[r]);
            if (!__all(lm <= mi + 11.5f)) {    // rare rescale path
                float pm = fmaxf(lm, __shfl_xor(lm, 32));
                float mn = fmaxf(mi, pm);
                float sf = fast_exp2(mi - mn);
                si *= sf;
                #pragma unroll
                for (int r = 0; r < 16; ++r) {
                    const int qloc = (r & 3) + 8*(r >> 2) + 4*hi;
                    float sfq = __shfl(sf, qloc);
                    o0[r] *= sfq; o1[r] *= sfq;
                }
                mi = mn;
            }
            float e[16];
            float psum = 0.f;
            #pragma unroll
            for (int r = 0; r < 16; ++r) {
                e[r] = fast_exp2(s[r] - mi);
                psum += e[r];
            }
            si += psum;
            // ---- P A-frags in-register + PV ----
            #pragma unroll
            for (int s2 = 0; s2 < 2; ++s2) {
                unsigned c0 = cvtpk_bf16(e[8*s2 + 0], e[8*s2 + 1]);
                unsigned c1 = cvtpk_bf16(e[8*s2 + 2], e[8*s2 + 3]);
                unsigned c2 = cvtpk_bf16(e[8*s2 + 4], e[8*s2 + 5]);
                unsigned c3 = cvtpk_bf16(e[8*s2 + 6], e[8*s2 + 7]);
                asm("v_permlane32_swap_b32 %0, %1" : "+v"(c0), "+v"(c2));
                asm("v_permlane32_swap_b32 %0, %1" : "+v"(c1), "+v"(c3));
                union { unsigned u[4]; s16x8 v; } pa;
                pa.u[0] = c0; pa.u[1] = c1; pa.u[2] = c2; pa.u[3] = c3;
                const int kc = kti*32 + 16*s2 + 8*hi;
                s16x8 vb0 = *(const s16x8*)&Vs[swz(lq,      kc)];
                s16x8 vb1 = *(const s16x8*)&Vs[swz(32 + lq, kc)];
                o0 = __builtin_amdgcn_mfma_f32_32x32x16_bf16(pa.v, vb0, o0, 0, 0, 0);
                o1 = __builtin_amdgcn_mfma_f32_32x32x16_bf16(pa.v, vb1, o1, 0, 0, 0);
            }
        }
    }
    // ---- epilogue: write UNNORMALIZED partial + (m, s) per q-row ----
    float sfull = si + __shfl_xor(si, 32);
    if (hi == 0) {   // one lane per q-row (mi identical across the two halves)
        const int row = bh * TT + qw0 + lq;
        ms[seg*MS_SEG + row]            = mi;
        ms[2*MS_SEG + seg*MS_SEG + row] = sfull;
    }
    unsigned short* op = seg ? oB : oA;
    #pragma unroll
    for (int r = 0; r < 16; ++r) {
        const int qloc = (r & 3) + 8*(r >> 2) + 4*hi;
        size_t row = (size_t)(b*TT + qw0 + qloc) * D_MODEL + h*64;
        op[row + lq]      = f2bf(o0[r]);
        op[row + 32 + lq] = f2bf(o1[r]);
    }
}

// ---------------- merge: Y = (oA*2^(m0-m) + oB*2^(m1-m)) / (s0*.. + s1*..) --
__launch_bounds__(256)
__global__ void merge_kernel(const unsigned short* __restrict__ oA,
                             const unsigned short* __restrict__ oB,
                             const float* __restrict__ ms,
                             unsigned short* __restrict__ Yw) {
    const int gid = blockIdx.x * 256 + threadIdx.x;
    const int e = gid * 8;                       // element idx, 8 per thread
    const int t = e / D_MODEL;                   // 0..4095
    const int c = e % D_MODEL;
    const int b = t >> 11, q = t & 2047;
    const int h = c >> 6;
    const int row = (b * N_HEADS + h) * TT + q;
    float m0 = ms[row],            m1 = ms[MS_SEG + row];
    float s0 = ms[2*MS_SEG + row], s1 = ms[3*MS_SEG + row];
    float m  = fmaxf(m0, m1);
    float a0 = fast_exp2(m0 - m), a1 = fast_exp2(m1 - m);
    float inv = 1.f / (s0 * a0 + s1 * a1);
    float w0 = a0 * inv, w1 = a1 * inv;
    s16x8 va = *(const s16x8*)&oA[e];
    s16x8 vb = *(const s16x8*)&oB[e];
    s16x8 out;
    #pragma unroll
    for (int j = 0; j < 8; ++j)
        out[j] = (short)f2bf(bf2f((unsigned short)va[j]) * w0 +
                             bf2f((unsigned short)vb[j]) * w1);
    *(s16x8*)&Yw[e] = out;
}

// ---------------- proj GEMM: Y[4096,768]bf16 x Wt[768,768]bf16 + b -> fp32 --
__launch_bounds__(256)
__global__ void proj_kernel(const unsigned short* __restrict__ Y, const unsigned short* __restrict__ Wt,
                            const float* __restrict__ bias, float* __restrict__ Out) {
    __shared__ unsigned short As[128][40];
    __shared__ unsigned short Bs[128][40];
    const int m0 = blockIdx.y * 128;
    const int n0 = blockIdx.x * 128;
    const int tid = threadIdx.x;
    const int l  = tid & 63;
    const int w  = tid >> 6;
    const int wr = w >> 1, wc = w & 1;
    const int lr = l & 15, lk = (l >> 4) * 8, li = (l >> 4) * 4;

    f32x4 acc[4][4] = {};
    for (int kt = 0; kt < D_MODEL; kt += 32) {
        #pragma unroll
        for (int p = 0; p < 2; ++p) {
            int ch = tid * 2 + p;
            int r = ch >> 2;
            int c = (ch & 3) * 8;
            *(int4*)&As[r][c] = *(const int4*)&Y[(size_t)(m0 + r) * D_MODEL + kt + c];
            *(int4*)&Bs[r][c] = *(const int4*)&Wt[(size_t)(n0 + r) * D_MODEL + kt + c];
        }
        __syncthreads();
        s16x8 a[4], bf[4];
        #pragma unroll
        for (int mi = 0; mi < 4; ++mi)
            a[mi] = *(const s16x8*)&As[wr*64 + mi*16 + lr][lk];
        #pragma unroll
        for (int ni = 0; ni < 4; ++ni)
            bf[ni] = *(const s16x8*)&Bs[wc*64 + ni*16 + lr][lk];
        #pragma unroll
        for (int mi = 0; mi < 4; ++mi)
            #pragma unroll
            for (int ni = 0; ni < 4; ++ni)
                acc[mi][ni] = __builtin_amdgcn_mfma_f32_16x16x32_bf16(a[mi], bf[ni], acc[mi][ni], 0, 0, 0);
        __syncthreads();
    }
    #pragma unroll
    for (int ni = 0; ni < 4; ++ni) {
        int ng = n0 + wc*64 + ni*16 + lr;
        float bv = bias[ng];
        #pragma unroll
        for (int mj = 0; mj < 4; ++mj)
            #pragma unroll
            for (int i = 0; i < 4; ++i) {
                int t = m0 + wr*64 + mj*16 + li + i;
                Out[(size_t)t*D_MODEL + ng] = acc[mj][ni][i] + bv;
            }
    }
}

extern "C" void kernel_launch(void* const* d_in, const int* in_sizes, int n_in,
                              void* d_out, int out_size, void* d_ws, size_t ws_size,
                              hipStream_t stream) {
    const float* x      = (const float*)d_in[0];
    const float* w_attn = (const float*)d_in[1];
    const float* b_attn = (const float*)d_in[2];
    const float* w_proj = (const float*)d_in[3];
    const float* b_proj = (const float*)d_in[4];
    float* out = (float*)d_out;

    unsigned short* wt_attn = (unsigned short*)d_ws;                       // 2304*768
    unsigned short* wt_proj = wt_attn + (size_t)N_QKV * D_MODEL;           // 768*768
    unsigned short* Qw      = wt_proj + (size_t)D_MODEL * D_MODEL;
    unsigned short* Kw      = Qw + (size_t)M_TOK * D_MODEL;
    unsigned short* Vw      = Kw + (size_t)M_TOK * D_MODEL;
    unsigned short* Yw      = Vw + (size_t)M_TOK * D_MODEL;
    unsigned short* Xb      = Yw + (size_t)M_TOK * D_MODEL;
    unsigned short* Vtw     = Xb;              // Xb dead after qkv; reuse for V^T
    unsigned short* oA      = Vw;              // Vw dead after vtrans: seg0 partial
    unsigned short* oB      = Yw;              // seg1 partial, merged in place
    float*          msbuf   = (float*)d_ws;    // wt_attn region dead after qkv

    hipLaunchKernelGGL(xbf_kernel, dim3(M_TOK*D_MODEL/2048), dim3(256), 0, stream, x, Xb);
    hipLaunchKernelGGL(wtrans_kernel, dim3(N_QKV/32, D_MODEL/32, 2), dim3(256), 0, stream,
                       w_attn, w_proj, wt_attn, wt_proj);
    hipLaunchKernelGGL(qkv_kernel, dim3(N_QKV/128, M_TOK/128), dim3(256), 0, stream,
                       Xb, wt_attn, b_attn, Qw, Kw, Vw);
    hipLaunchKernelGGL(vtrans_kernel, dim3(TT/64, BB*N_HEADS), dim3(256), 0, stream,
                       Vw, Vtw);
    hipLaunchKernelGGL(attn_kernel, dim3(32, BB*N_HEADS), dim3(256), 0, stream,
                       Qw, Kw, Vtw, oA, oB, msbuf);
    hipLaunchKernelGGL(merge_kernel, dim3(M_TOK*D_MODEL/8/256), dim3(256), 0, stream,
                       oA, oB, msbuf, Yw);
    hipLaunchKernelGGL(proj_kernel, dim3(D_MODEL/128, M_TOK/128), dim3(256), 0, stream,
                       Yw, wt_proj, b_proj, out);
}